// Round 20
// baseline (255.308 us; speedup 1.0000x reference)
//
#include <hip/hip_runtime.h>
#include <math.h>

#define HW 262144          // 512*512
#define NB 4
#define NC 4
#define ND 32
#define NPIX (NB * HW)     // 1048576
#define NG 262144          // float4 pixel-groups (NPIX/4)
#define EPSF 1e-8f

// ws header (floats):
#define OFF_SUMS    0      // 1024
#define OFF_COUNTS  1024   // 32
#define OFF_CENTERS 1056   // 1024
#define OFF_CNORM   2080   // 32
#define OFF_PART    2112   // 256
#define HDR_BYTES   9472
// byte offsets after header (meta only, ~13 MB):
#define OFF_REC     HDR_BYTES                     // u32[NG]    1 MB
#define OFF_CPK     (OFF_REC + 4L * NG)           // uint4-grouped conf pairs, 4 MB
#define OFF_CEM     (OFF_CPK + 16L * NG)          // float4[NG] 4 MB
#define OFF_CEA     (OFF_CEM + 16L * NG)          // float4[NG] 4 MB

#define ELEM(v,e) ((e)==0?(v).x:(e)==1?(v).y:(e)==2?(v).z:(v).w)
#define W32(q,i)  ((i)==0?(q).x:(i)==1?(q).y:(i)==2?(q).z:(q).w)

__device__ __forceinline__ float wave_sum64(float v) {
#pragma unroll
  for (int off = 32; off > 0; off >>= 1) v += __shfl_xor(v, off, 64);
  return v;
}
__device__ __forceinline__ unsigned short f2bf(float f) {  // RNE
  unsigned u = __float_as_uint(f);
  return (unsigned short)((u + 0x7fffu + ((u >> 16) & 1u)) >> 16);
}

// -------- Pass A2s: per-pixel stats only (proven ~15 us) --------
__global__ __launch_bounds__(256) void passA2s(
    const float* __restrict__ pm, const float* __restrict__ pa,
    unsigned* __restrict__ recu, uint4* __restrict__ cpk4,
    float4* __restrict__ cem4, float4* __restrict__ cea4) {
  int p4 = blockIdx.x * 256 + threadIdx.x;
  int b = p4 >> 16;
  int px4 = p4 & 0xFFFF;
  const float4* xb = (const float4*)pm + (((long)b * NC) << 16) + px4;
  const float4* yb = (const float4*)pa + (((long)b * NC) << 16) + px4;
  float4 X0 = xb[0], X1 = xb[1 << 16], X2 = xb[2 << 16], X3 = xb[3 << 16];
  float4 Y0 = yb[0], Y1 = yb[1 << 16], Y2 = yb[2 << 16], Y3 = yb[3 << 16];
  float4 cem, cea;
  uint4 cpk;
  unsigned ru = 0;
#pragma unroll
  for (int e = 0; e < 4; ++e) {
    float x0 = ELEM(X0, e), x1 = ELEM(X1, e), x2 = ELEM(X2, e), x3 = ELEM(X3, e);
    float y0 = ELEM(Y0, e), y1 = ELEM(Y1, e), y2 = ELEM(Y2, e), y3 = ELEM(Y3, e);
    int hm = 0; float bm = x0;
    if (x1 > bm) { bm = x1; hm = 1; }
    if (x2 > bm) { bm = x2; hm = 2; }
    if (x3 > bm) { bm = x3; hm = 3; }
    int ha = 0; float ba = y0;
    if (y1 > ba) { ba = y1; ha = 1; }
    if (y2 > ba) { ba = y2; ha = 2; }
    if (y3 > ba) { ba = y3; ha = 3; }
    float sem = expf(x0 - bm) + expf(x1 - bm) + expf(x2 - bm) + expf(x3 - bm);
    float sea = expf(y0 - ba) + expf(y1 - ba) + expf(y2 - ba) + expf(y3 - ba);
    float confm = 1.0f / sem, confa = 1.0f / sea;
    int mk = (confm >= confa) ? 1 : 0;
    int lab = mk ? hm : ha;
    float xl = lab == 0 ? x0 : lab == 1 ? x1 : lab == 2 ? x2 : x3;
    float yl = lab == 0 ? y0 : lab == 1 ? y1 : lab == 2 ? y2 : y3;
    float vem = bm - xl + logf(sem);
    float vea = ba - yl + logf(sea);
    unsigned pk = (unsigned)f2bf(confm) | ((unsigned)f2bf(confa) << 16);
    if (e == 0) { cem.x = vem; cea.x = vea; cpk.x = pk; }
    if (e == 1) { cem.y = vem; cea.y = vea; cpk.y = pk; }
    if (e == 2) { cem.z = vem; cea.z = vea; cpk.z = pk; }
    if (e == 3) { cem.w = vem; cea.w = vea; cpk.w = pk; }
    ru |= (unsigned)(hm | (ha << 2) | (mk << 4)) << (8 * e);
  }
  cem4[p4] = cem; cea4[p4] = cea; cpk4[p4] = cpk; recu[p4] = ru;
}

// -------- countK: per-(b,map,cls) pixel counts from recu (proven ~3 us) ---
__global__ __launch_bounds__(256) void countK(const unsigned* __restrict__ recu,
                                              float* __restrict__ counts) {
  int b = blockIdx.y;
  int t = blockIdx.x * 256 + threadIdx.x;
  float c[8];
#pragma unroll
  for (int j = 0; j < 8; ++j) c[j] = 0.f;
#pragma unroll
  for (int k = 0; k < 8; ++k) {
    unsigned ru = recu[(b << 16) + t + k * 8192];
#pragma unroll
    for (int e = 0; e < 4; ++e) {
      unsigned r = (ru >> (8 * e)) & 0xffu;
      int hm = r & 3, ha = (r >> 2) & 3;
      c[0] += hm == 0 ? 1.f : 0.f; c[1] += hm == 1 ? 1.f : 0.f;
      c[2] += hm == 2 ? 1.f : 0.f; c[3] += hm == 3 ? 1.f : 0.f;
      c[4] += ha == 0 ? 1.f : 0.f; c[5] += ha == 1 ? 1.f : 0.f;
      c[6] += ha == 2 ? 1.f : 0.f; c[7] += ha == 3 ? 1.f : 0.f;
    }
  }
  int lane = threadIdx.x & 63;
#pragma unroll
  for (int j = 0; j < 8; ++j) {
    float v = wave_sum64(c[j]);
    if (lane == 0) atomicAdd(&counts[(j >> 2) * 16 + b * 4 + (j & 3)], v);
  }
}

// -------- passB6: center sums, 1-WAVE blocks, no LDS, no barrier ----------
// Same loop body as passB5 (94 us @ 62% occupancy). Occupancy probe: 64-thread
// blocks (8192 total), __launch_bounds__(64,8) = 8 waves/SIMD declared, no
// __syncthreads (wave-private epilogue: butterfly + direct atomics).
__global__ __launch_bounds__(64, 8) void passB6(
    const float* __restrict__ fm, const float* __restrict__ fa,
    const unsigned* __restrict__ recu, const uint4* __restrict__ cpk4,
    float* __restrict__ sums) {
  int b = blockIdx.y >> 4;
  int dp = blockIdx.y & 15;
  int d0 = dp * 2;
  int lane = threadIdx.x;           // 0..63, one wave per block
  bool b0 = lane & 1, b1 = lane & 2, b2 = lane & 4;

  const float4* fm0 = (const float4*)fm + (((long)(b * ND + d0)) << 16);
  const float4* fa0 = (const float4*)fa + (((long)(b * ND + d0)) << 16);
  const float4* fm1 = fm0 + (1L << 16);
  const float4* fa1 = fa0 + (1L << 16);
  const unsigned* ruP = recu + ((long)b << 16);
  const uint4* ckP = cpk4 + ((long)b << 16);

  float acc[8][2];                  // [bin][dj] — constant-indexed only
#pragma unroll
  for (int c = 0; c < 8; ++c) {
    acc[c][0] = 0.f;
    acc[c][1] = 0.f;
  }

#pragma unroll 4
  for (int k = 0; k < 8; ++k) {
    int g = blockIdx.x * 512 + k * 64 + lane;
    unsigned ru = ruP[g];
    uint4 ck = ckP[g];
    float4 vm0 = fm0[g];
    float4 va0 = fa0[g];
    float4 vm1 = fm1[g];
    float4 va1 = fa1[g];
#pragma unroll
    for (int e = 0; e < 4; ++e) {
      unsigned r = (ru >> (8 * e)) & 0xffu;
      unsigned pk = W32(ck, e);
      int hm = r & 3, ha = (r >> 2) & 3, mk = (r >> 4) & 1;
      float cm = __uint_as_float(pk << 16);
      float ca = __uint_as_float(pk & 0xffff0000u);
      float p0 = mk ? ELEM(vm0, e) : ELEM(va0, e);
      float p1 = mk ? ELEM(vm1, e) : ELEM(va1, e);
#pragma unroll
      for (int c = 0; c < 4; ++c) {
        float wm = (hm == c) ? cm : 0.f;
        float wa = (ha == c) ? ca : 0.f;
        acc[c][0] = fmaf(wm, p0, acc[c][0]);
        acc[c][1] = fmaf(wm, p1, acc[c][1]);
        acc[4 + c][0] = fmaf(wa, p0, acc[4 + c][0]);
        acc[4 + c][1] = fmaf(wa, p1, acc[4 + c][1]);
      }
    }
  }

  // epilogue: per dj, multi-value butterfly (10 shfl) + direct atomics
#pragma unroll
  for (int j = 0; j < 2; ++j) {
    float v0 = acc[0][j], v1 = acc[1][j], v2 = acc[2][j], v3 = acc[3][j];
    float v4 = acc[4][j], v5 = acc[5][j], v6 = acc[6][j], v7 = acc[7][j];
    float w0 = (b0 ? v1 : v0) + __shfl_xor(b0 ? v0 : v1, 1, 64);
    float w1 = (b0 ? v3 : v2) + __shfl_xor(b0 ? v2 : v3, 1, 64);
    float w2 = (b0 ? v5 : v4) + __shfl_xor(b0 ? v4 : v5, 1, 64);
    float w3 = (b0 ? v7 : v6) + __shfl_xor(b0 ? v6 : v7, 1, 64);
    float x0 = (b1 ? w1 : w0) + __shfl_xor(b1 ? w0 : w1, 2, 64);
    float x1 = (b1 ? w3 : w2) + __shfl_xor(b1 ? w2 : w3, 2, 64);
    float y = (b2 ? x1 : x0) + __shfl_xor(b2 ? x0 : x1, 4, 64);
    y += __shfl_xor(y, 8, 64);
    y += __shfl_xor(y, 16, 64);
    y += __shfl_xor(y, 32, 64);
    if (lane < 8) {
      int map = lane >> 2, cls = lane & 3;
      atomicAdd(&sums[((map * NB + b) * NC + cls) * ND + d0 + j], y);
    }
  }
}

// -------- Pass C: finalize centers + norms (1 block) --------
__global__ __launch_bounds__(1024) void passC(
    const float* __restrict__ sums, const float* __restrict__ counts,
    float* __restrict__ centers, float* __restrict__ cnorm) {
  int t = threadIdx.x;
  int g = t >> 5;
  float cv = sums[t] / fmaxf(counts[g], 1.f);
  centers[t] = cv;
  float s = cv * cv;
#pragma unroll
  for (int off = 16; off > 0; off >>= 1) s += __shfl_xor(s, off, 32);
  if ((t & 31) == 0) cnorm[g] = fmaxf(sqrtf(s), EPSF);
}

// -------- Pass D: cosine + weighted reductions (R2-proven f32) --------
__global__ __launch_bounds__(256) void passDf32(
    const float* __restrict__ fm, const float* __restrict__ fa,
    const unsigned* __restrict__ recu, const float4* __restrict__ cem4,
    const float4* __restrict__ cea4, const float* __restrict__ centers,
    const float* __restrict__ cnorm, float* __restrict__ part) {
  __shared__ float sc[1024];
  __shared__ float scn[32];
  __shared__ float red[4][4];
  for (int i = threadIdx.x; i < 1024; i += 256) {
    int d = i & 31, cls = (i >> 5) & 3, bb = (i >> 7) & 3, mp = i >> 9;
    sc[d * 32 + mp * 16 + bb * 4 + cls] = centers[i];
  }
  if (threadIdx.x < 32) scn[threadIdx.x] = cnorm[threadIdx.x];
  __syncthreads();

  int p4 = blockIdx.x * 256 + threadIdx.x;
  int b = p4 >> 16;
  int px4 = p4 & 0xFFFF;
  unsigned ru = recu[p4];
  int im[4], ia[4], mk[4];
#pragma unroll
  for (int e = 0; e < 4; ++e) {
    unsigned r = (ru >> (8 * e)) & 0xffu;
    im[e] = b * 4 + (r & 3);
    ia[e] = 16 + b * 4 + ((r >> 2) & 3);
    mk[e] = (r >> 4) & 1;
  }
  const float4* fmb = (const float4*)fm + (((long)(b * ND)) << 16) + px4;
  const float4* fab = (const float4*)fa + (((long)(b * ND)) << 16) + px4;
  float4 nm = {0.f, 0.f, 0.f, 0.f}, na = {0.f, 0.f, 0.f, 0.f},
         fn2 = {0.f, 0.f, 0.f, 0.f};
#pragma unroll 16
  for (int d = 0; d < ND; ++d) {
    float4 vm = fmb[(long)d << 16];
    float4 va = fab[(long)d << 16];
#pragma unroll
    for (int e = 0; e < 4; ++e) {
      float ps = mk[e] ? ELEM(vm, e) : ELEM(va, e);
      float cim = sc[d * 32 + im[e]];
      float cia = sc[d * 32 + ia[e]];
      if (e == 0) { nm.x = fmaf(ps, cim, nm.x); na.x = fmaf(ps, cia, na.x); fn2.x = fmaf(ps, ps, fn2.x); }
      if (e == 1) { nm.y = fmaf(ps, cim, nm.y); na.y = fmaf(ps, cia, na.y); fn2.y = fmaf(ps, ps, fn2.y); }
      if (e == 2) { nm.z = fmaf(ps, cim, nm.z); na.z = fmaf(ps, cia, na.z); fn2.z = fmaf(ps, ps, fn2.z); }
      if (e == 3) { nm.w = fmaf(ps, cim, nm.w); na.w = fmaf(ps, cia, na.w); fn2.w = fmaf(ps, ps, fn2.w); }
    }
  }
  float4 cem = cem4[p4], cea = cea4[p4];
  float s0 = 0.f, s1 = 0.f, s2 = 0.f, s3 = 0.f;
#pragma unroll
  for (int e = 0; e < 4; ++e) {
    float fn = fmaxf(sqrtf(ELEM(fn2, e)), EPSF);
    float rm = ELEM(nm, e) / (fn * scn[im[e]]);
    float ra = ELEM(na, e) / (fn * scn[ia[e]]);
    s0 = fmaf(ELEM(cem, e), ra, s0);
    s1 += ra;
    s2 = fmaf(ELEM(cea, e), rm, s2);
    s3 += rm;
  }
  s0 = wave_sum64(s0); s1 = wave_sum64(s1);
  s2 = wave_sum64(s2); s3 = wave_sum64(s3);
  int wave = threadIdx.x >> 6, lane = threadIdx.x & 63;
  if (lane == 0) { red[wave][0] = s0; red[wave][1] = s1; red[wave][2] = s2; red[wave][3] = s3; }
  __syncthreads();
  if (threadIdx.x < 4) {
    float v = red[0][threadIdx.x] + red[1][threadIdx.x] +
              red[2][threadIdx.x] + red[3][threadIdx.x];
    atomicAdd(&part[(blockIdx.x & 63) * 4 + threadIdx.x], v);
  }
}

// -------- Pass E: final scalar --------
__global__ __launch_bounds__(64) void passE(const float* __restrict__ part,
                                            float* __restrict__ out) {
  int t = threadIdx.x;
  float a0 = part[t * 4 + 0], a1 = part[t * 4 + 1];
  float a2 = part[t * 4 + 2], a3 = part[t * 4 + 3];
  a0 = wave_sum64(a0); a1 = wave_sum64(a1);
  a2 = wave_sum64(a2); a3 = wave_sum64(a3);
  if (t == 0) out[0] = a0 / a1 + a2 / a3;
}

extern "C" void kernel_launch(void* const* d_in, const int* in_sizes, int n_in,
                              void* d_out, int out_size, void* d_ws, size_t ws_size,
                              hipStream_t stream) {
  const float* pm = (const float*)d_in[0];
  const float* pa = (const float*)d_in[1];
  const float* fm = (const float*)d_in[2];
  const float* fa = (const float*)d_in[3];

  float* wsf = (float*)d_ws;
  float* sums = wsf + OFF_SUMS;
  float* counts = wsf + OFF_COUNTS;
  float* centers = wsf + OFF_CENTERS;
  float* cnorm = wsf + OFF_CNORM;
  float* part = wsf + OFF_PART;
  char* wsb = (char*)d_ws;
  unsigned* recu = (unsigned*)(wsb + OFF_REC);
  uint4* cpk4 = (uint4*)(wsb + OFF_CPK);
  float4* cem4 = (float4*)(wsb + OFF_CEM);
  float4* cea4 = (float4*)(wsb + OFF_CEA);

  hipMemsetAsync(d_ws, 0, HDR_BYTES, stream);
  passA2s<<<1024, 256, 0, stream>>>(pm, pa, recu, cpk4, cem4, cea4);
  countK<<<dim3(32, 4), 256, 0, stream>>>(recu, counts);
  passB6<<<dim3(128, 64), 64, 0, stream>>>(fm, fa, recu, cpk4, sums);
  passC<<<1, 1024, 0, stream>>>(sums, counts, centers, cnorm);
  passDf32<<<1024, 256, 0, stream>>>(fm, fa, recu, cem4, cea4, centers,
                                     cnorm, part);
  passE<<<1, 64, 0, stream>>>(part, (float*)d_out);
}

// Round 21
// 189.415 us; speedup vs baseline: 1.3479x; 1.3479x over previous
//
#include <hip/hip_runtime.h>
#include <math.h>

#define HW 262144          // 512*512
#define NB 4
#define NC 4
#define ND 32
#define NPIX (NB * HW)     // 1048576
#define NG 262144          // float4 pixel-groups (NPIX/4)
#define EPSF 1e-8f

// ws header (floats):
#define OFF_SUMS    0      // 1024
#define OFF_COUNTS  1024   // 32
#define OFF_CENTERS 1056   // 1024
#define OFF_CNORM   2080   // 32
#define OFF_PART    2112   // 256
#define HDR_BYTES   9472
// byte offsets after header (meta only, ~13 MB):
#define OFF_REC     HDR_BYTES                     // u32[NG]    1 MB
#define OFF_CPK     (OFF_REC + 4L * NG)           // uint4-grouped conf pairs, 4 MB
#define OFF_CEM     (OFF_CPK + 16L * NG)          // float4[NG] 4 MB
#define OFF_CEA     (OFF_CEM + 16L * NG)          // float4[NG] 4 MB

#define ELEM(v,e) ((e)==0?(v).x:(e)==1?(v).y:(e)==2?(v).z:(v).w)
#define W32(q,i)  ((i)==0?(q).x:(i)==1?(q).y:(i)==2?(q).z:(q).w)

__device__ __forceinline__ float wave_sum64(float v) {
#pragma unroll
  for (int off = 32; off > 0; off >>= 1) v += __shfl_xor(v, off, 64);
  return v;
}
__device__ __forceinline__ unsigned short f2bf(float f) {  // RNE
  unsigned u = __float_as_uint(f);
  return (unsigned short)((u + 0x7fffu + ((u >> 16) & 1u)) >> 16);
}

// -------- Pass A2s: per-pixel stats only (proven ~15 us) --------
__global__ __launch_bounds__(256) void passA2s(
    const float* __restrict__ pm, const float* __restrict__ pa,
    unsigned* __restrict__ recu, uint4* __restrict__ cpk4,
    float4* __restrict__ cem4, float4* __restrict__ cea4) {
  int p4 = blockIdx.x * 256 + threadIdx.x;
  int b = p4 >> 16;
  int px4 = p4 & 0xFFFF;
  const float4* xb = (const float4*)pm + (((long)b * NC) << 16) + px4;
  const float4* yb = (const float4*)pa + (((long)b * NC) << 16) + px4;
  float4 X0 = xb[0], X1 = xb[1 << 16], X2 = xb[2 << 16], X3 = xb[3 << 16];
  float4 Y0 = yb[0], Y1 = yb[1 << 16], Y2 = yb[2 << 16], Y3 = yb[3 << 16];
  float4 cem, cea;
  uint4 cpk;
  unsigned ru = 0;
#pragma unroll
  for (int e = 0; e < 4; ++e) {
    float x0 = ELEM(X0, e), x1 = ELEM(X1, e), x2 = ELEM(X2, e), x3 = ELEM(X3, e);
    float y0 = ELEM(Y0, e), y1 = ELEM(Y1, e), y2 = ELEM(Y2, e), y3 = ELEM(Y3, e);
    int hm = 0; float bm = x0;
    if (x1 > bm) { bm = x1; hm = 1; }
    if (x2 > bm) { bm = x2; hm = 2; }
    if (x3 > bm) { bm = x3; hm = 3; }
    int ha = 0; float ba = y0;
    if (y1 > ba) { ba = y1; ha = 1; }
    if (y2 > ba) { ba = y2; ha = 2; }
    if (y3 > ba) { ba = y3; ha = 3; }
    float sem = expf(x0 - bm) + expf(x1 - bm) + expf(x2 - bm) + expf(x3 - bm);
    float sea = expf(y0 - ba) + expf(y1 - ba) + expf(y2 - ba) + expf(y3 - ba);
    float confm = 1.0f / sem, confa = 1.0f / sea;
    int mk = (confm >= confa) ? 1 : 0;
    int lab = mk ? hm : ha;
    float xl = lab == 0 ? x0 : lab == 1 ? x1 : lab == 2 ? x2 : x3;
    float yl = lab == 0 ? y0 : lab == 1 ? y1 : lab == 2 ? y2 : y3;
    float vem = bm - xl + logf(sem);
    float vea = ba - yl + logf(sea);
    unsigned pk = (unsigned)f2bf(confm) | ((unsigned)f2bf(confa) << 16);
    if (e == 0) { cem.x = vem; cea.x = vea; cpk.x = pk; }
    if (e == 1) { cem.y = vem; cea.y = vea; cpk.y = pk; }
    if (e == 2) { cem.z = vem; cea.z = vea; cpk.z = pk; }
    if (e == 3) { cem.w = vem; cea.w = vea; cpk.w = pk; }
    ru |= (unsigned)(hm | (ha << 2) | (mk << 4)) << (8 * e);
  }
  cem4[p4] = cem; cea4[p4] = cea; cpk4[p4] = cpk; recu[p4] = ru;
}

// -------- countK: per-(b,map,cls) pixel counts from recu (proven ~3 us) ---
__global__ __launch_bounds__(256) void countK(const unsigned* __restrict__ recu,
                                              float* __restrict__ counts) {
  int b = blockIdx.y;
  int t = blockIdx.x * 256 + threadIdx.x;
  float c[8];
#pragma unroll
  for (int j = 0; j < 8; ++j) c[j] = 0.f;
#pragma unroll
  for (int k = 0; k < 8; ++k) {
    unsigned ru = recu[(b << 16) + t + k * 8192];
#pragma unroll
    for (int e = 0; e < 4; ++e) {
      unsigned r = (ru >> (8 * e)) & 0xffu;
      int hm = r & 3, ha = (r >> 2) & 3;
      c[0] += hm == 0 ? 1.f : 0.f; c[1] += hm == 1 ? 1.f : 0.f;
      c[2] += hm == 2 ? 1.f : 0.f; c[3] += hm == 3 ? 1.f : 0.f;
      c[4] += ha == 0 ? 1.f : 0.f; c[5] += ha == 1 ? 1.f : 0.f;
      c[6] += ha == 2 ? 1.f : 0.f; c[7] += ha == 3 ? 1.f : 0.f;
    }
  }
  int lane = threadIdx.x & 63;
#pragma unroll
  for (int j = 0; j < 8; ++j) {
    float v = wave_sum64(c[j]);
    if (lane == 0) atomicAdd(&counts[(j >> 2) * 16 + b * 4 + (j & 3)], v);
  }
}

// -------- passB5: center sums, 2 d-planes/block — FULL UNROLL, cap 256 ----
// R19 body (94 us) with the untried config: full 8-iter unroll under
// __launch_bounds__(256,1). Demand ~205 regs <= 256 cap -> no spill, 48
// loads in flight/wave (pfWrite recipe: deep window = 6 TB/s cold).
__global__ __launch_bounds__(256, 1) void passB5(
    const float* __restrict__ fm, const float* __restrict__ fa,
    const unsigned* __restrict__ recu, const uint4* __restrict__ cpk4,
    float* __restrict__ sums) {
  __shared__ float lred[4][16];     // [wave][dj*8 + bin]
  int b = blockIdx.y >> 4;
  int dp = blockIdx.y & 15;
  int d0 = dp * 2;
  int wave = threadIdx.x >> 6, lane = threadIdx.x & 63;
  bool b0 = lane & 1, b1 = lane & 2, b2 = lane & 4;

  const float4* fm0 = (const float4*)fm + (((long)(b * ND + d0)) << 16);
  const float4* fa0 = (const float4*)fa + (((long)(b * ND + d0)) << 16);
  const float4* fm1 = fm0 + (1L << 16);
  const float4* fa1 = fa0 + (1L << 16);
  const unsigned* ruP = recu + ((long)b << 16);
  const uint4* ckP = cpk4 + ((long)b << 16);

  float acc[8][2];                  // [bin][dj] — constant-indexed only
#pragma unroll
  for (int c = 0; c < 8; ++c) {
    acc[c][0] = 0.f;
    acc[c][1] = 0.f;
  }

#pragma unroll
  for (int k = 0; k < 8; ++k) {
    int g = blockIdx.x * 2048 + k * 256 + threadIdx.x;
    unsigned ru = ruP[g];
    uint4 ck = ckP[g];
    float4 vm0 = fm0[g];
    float4 va0 = fa0[g];
    float4 vm1 = fm1[g];
    float4 va1 = fa1[g];
#pragma unroll
    for (int e = 0; e < 4; ++e) {
      unsigned r = (ru >> (8 * e)) & 0xffu;
      unsigned pk = W32(ck, e);
      int hm = r & 3, ha = (r >> 2) & 3, mk = (r >> 4) & 1;
      float cm = __uint_as_float(pk << 16);
      float ca = __uint_as_float(pk & 0xffff0000u);
      float p0 = mk ? ELEM(vm0, e) : ELEM(va0, e);
      float p1 = mk ? ELEM(vm1, e) : ELEM(va1, e);
#pragma unroll
      for (int c = 0; c < 4; ++c) {
        float wm = (hm == c) ? cm : 0.f;
        float wa = (ha == c) ? ca : 0.f;
        acc[c][0] = fmaf(wm, p0, acc[c][0]);
        acc[c][1] = fmaf(wm, p1, acc[c][1]);
        acc[4 + c][0] = fmaf(wa, p0, acc[4 + c][0]);
        acc[4 + c][1] = fmaf(wa, p1, acc[4 + c][1]);
      }
    }
  }

  // epilogue: per dj, R14-proven multi-value butterfly (10 shfl)
#pragma unroll
  for (int j = 0; j < 2; ++j) {
    float v0 = acc[0][j], v1 = acc[1][j], v2 = acc[2][j], v3 = acc[3][j];
    float v4 = acc[4][j], v5 = acc[5][j], v6 = acc[6][j], v7 = acc[7][j];
    float w0 = (b0 ? v1 : v0) + __shfl_xor(b0 ? v0 : v1, 1, 64);
    float w1 = (b0 ? v3 : v2) + __shfl_xor(b0 ? v2 : v3, 1, 64);
    float w2 = (b0 ? v5 : v4) + __shfl_xor(b0 ? v4 : v5, 1, 64);
    float w3 = (b0 ? v7 : v6) + __shfl_xor(b0 ? v6 : v7, 1, 64);
    float x0 = (b1 ? w1 : w0) + __shfl_xor(b1 ? w0 : w1, 2, 64);
    float x1 = (b1 ? w3 : w2) + __shfl_xor(b1 ? w2 : w3, 2, 64);
    float y = (b2 ? x1 : x0) + __shfl_xor(b2 ? x0 : x1, 4, 64);
    y += __shfl_xor(y, 8, 64);
    y += __shfl_xor(y, 16, 64);
    y += __shfl_xor(y, 32, 64);
    if (lane < 8) lred[wave][j * 8 + lane] = y;
  }
  __syncthreads();
  if (threadIdx.x < 16) {
    int t = threadIdx.x;            // t = dj*8 + bin
    float v = lred[0][t] + lred[1][t] + lred[2][t] + lred[3][t];
    int dj = t >> 3, bin = t & 7;
    int map = bin >> 2, cls = bin & 3;
    atomicAdd(&sums[((map * NB + b) * NC + cls) * ND + d0 + dj], v);
  }
}

// -------- Pass C: finalize centers + norms (1 block) --------
__global__ __launch_bounds__(1024) void passC(
    const float* __restrict__ sums, const float* __restrict__ counts,
    float* __restrict__ centers, float* __restrict__ cnorm) {
  int t = threadIdx.x;
  int g = t >> 5;
  float cv = sums[t] / fmaxf(counts[g], 1.f);
  centers[t] = cv;
  float s = cv * cv;
#pragma unroll
  for (int off = 16; off > 0; off >>= 1) s += __shfl_xor(s, off, 32);
  if ((t & 31) == 0) cnorm[g] = fmaxf(sqrtf(s), EPSF);
}

// -------- Pass D: cosine + weighted reductions (R2-proven f32) --------
__global__ __launch_bounds__(256) void passDf32(
    const float* __restrict__ fm, const float* __restrict__ fa,
    const unsigned* __restrict__ recu, const float4* __restrict__ cem4,
    const float4* __restrict__ cea4, const float* __restrict__ centers,
    const float* __restrict__ cnorm, float* __restrict__ part) {
  __shared__ float sc[1024];
  __shared__ float scn[32];
  __shared__ float red[4][4];
  for (int i = threadIdx.x; i < 1024; i += 256) {
    int d = i & 31, cls = (i >> 5) & 3, bb = (i >> 7) & 3, mp = i >> 9;
    sc[d * 32 + mp * 16 + bb * 4 + cls] = centers[i];
  }
  if (threadIdx.x < 32) scn[threadIdx.x] = cnorm[threadIdx.x];
  __syncthreads();

  int p4 = blockIdx.x * 256 + threadIdx.x;
  int b = p4 >> 16;
  int px4 = p4 & 0xFFFF;
  unsigned ru = recu[p4];
  int im[4], ia[4], mk[4];
#pragma unroll
  for (int e = 0; e < 4; ++e) {
    unsigned r = (ru >> (8 * e)) & 0xffu;
    im[e] = b * 4 + (r & 3);
    ia[e] = 16 + b * 4 + ((r >> 2) & 3);
    mk[e] = (r >> 4) & 1;
  }
  const float4* fmb = (const float4*)fm + (((long)(b * ND)) << 16) + px4;
  const float4* fab = (const float4*)fa + (((long)(b * ND)) << 16) + px4;
  float4 nm = {0.f, 0.f, 0.f, 0.f}, na = {0.f, 0.f, 0.f, 0.f},
         fn2 = {0.f, 0.f, 0.f, 0.f};
#pragma unroll 16
  for (int d = 0; d < ND; ++d) {
    float4 vm = fmb[(long)d << 16];
    float4 va = fab[(long)d << 16];
#pragma unroll
    for (int e = 0; e < 4; ++e) {
      float ps = mk[e] ? ELEM(vm, e) : ELEM(va, e);
      float cim = sc[d * 32 + im[e]];
      float cia = sc[d * 32 + ia[e]];
      if (e == 0) { nm.x = fmaf(ps, cim, nm.x); na.x = fmaf(ps, cia, na.x); fn2.x = fmaf(ps, ps, fn2.x); }
      if (e == 1) { nm.y = fmaf(ps, cim, nm.y); na.y = fmaf(ps, cia, na.y); fn2.y = fmaf(ps, ps, fn2.y); }
      if (e == 2) { nm.z = fmaf(ps, cim, nm.z); na.z = fmaf(ps, cia, na.z); fn2.z = fmaf(ps, ps, fn2.z); }
      if (e == 3) { nm.w = fmaf(ps, cim, nm.w); na.w = fmaf(ps, cia, na.w); fn2.w = fmaf(ps, ps, fn2.w); }
    }
  }
  float4 cem = cem4[p4], cea = cea4[p4];
  float s0 = 0.f, s1 = 0.f, s2 = 0.f, s3 = 0.f;
#pragma unroll
  for (int e = 0; e < 4; ++e) {
    float fn = fmaxf(sqrtf(ELEM(fn2, e)), EPSF);
    float rm = ELEM(nm, e) / (fn * scn[im[e]]);
    float ra = ELEM(na, e) / (fn * scn[ia[e]]);
    s0 = fmaf(ELEM(cem, e), ra, s0);
    s1 += ra;
    s2 = fmaf(ELEM(cea, e), rm, s2);
    s3 += rm;
  }
  s0 = wave_sum64(s0); s1 = wave_sum64(s1);
  s2 = wave_sum64(s2); s3 = wave_sum64(s3);
  int wave = threadIdx.x >> 6, lane = threadIdx.x & 63;
  if (lane == 0) { red[wave][0] = s0; red[wave][1] = s1; red[wave][2] = s2; red[wave][3] = s3; }
  __syncthreads();
  if (threadIdx.x < 4) {
    float v = red[0][threadIdx.x] + red[1][threadIdx.x] +
              red[2][threadIdx.x] + red[3][threadIdx.x];
    atomicAdd(&part[(blockIdx.x & 63) * 4 + threadIdx.x], v);
  }
}

// -------- Pass E: final scalar --------
__global__ __launch_bounds__(64) void passE(const float* __restrict__ part,
                                            float* __restrict__ out) {
  int t = threadIdx.x;
  float a0 = part[t * 4 + 0], a1 = part[t * 4 + 1];
  float a2 = part[t * 4 + 2], a3 = part[t * 4 + 3];
  a0 = wave_sum64(a0); a1 = wave_sum64(a1);
  a2 = wave_sum64(a2); a3 = wave_sum64(a3);
  if (t == 0) out[0] = a0 / a1 + a2 / a3;
}

extern "C" void kernel_launch(void* const* d_in, const int* in_sizes, int n_in,
                              void* d_out, int out_size, void* d_ws, size_t ws_size,
                              hipStream_t stream) {
  const float* pm = (const float*)d_in[0];
  const float* pa = (const float*)d_in[1];
  const float* fm = (const float*)d_in[2];
  const float* fa = (const float*)d_in[3];

  float* wsf = (float*)d_ws;
  float* sums = wsf + OFF_SUMS;
  float* counts = wsf + OFF_COUNTS;
  float* centers = wsf + OFF_CENTERS;
  float* cnorm = wsf + OFF_CNORM;
  float* part = wsf + OFF_PART;
  char* wsb = (char*)d_ws;
  unsigned* recu = (unsigned*)(wsb + OFF_REC);
  uint4* cpk4 = (uint4*)(wsb + OFF_CPK);
  float4* cem4 = (float4*)(wsb + OFF_CEM);
  float4* cea4 = (float4*)(wsb + OFF_CEA);

  hipMemsetAsync(d_ws, 0, HDR_BYTES, stream);
  passA2s<<<1024, 256, 0, stream>>>(pm, pa, recu, cpk4, cem4, cea4);
  countK<<<dim3(32, 4), 256, 0, stream>>>(recu, counts);
  passB5<<<dim3(32, 64), 256, 0, stream>>>(fm, fa, recu, cpk4, sums);
  passC<<<1, 1024, 0, stream>>>(sums, counts, centers, cnorm);
  passDf32<<<1024, 256, 0, stream>>>(fm, fa, recu, cem4, cea4, centers,
                                     cnorm, part);
  passE<<<1, 64, 0, stream>>>(part, (float*)d_out);
}

// Round 22
// 161.799 us; speedup vs baseline: 1.5779x; 1.1707x over previous
//
#include <hip/hip_runtime.h>
#include <math.h>

#define HW 262144          // 512*512
#define NB 4
#define NC 4
#define ND 32
#define NPIX (NB * HW)     // 1048576
#define NG 262144          // float4 pixel-groups (NPIX/4)
#define EPSF 1e-8f

// ws header (floats):
#define OFF_SUMS    0      // 1024
#define OFF_COUNTS  1024   // 32
#define OFF_CENTERS 1056   // 1024
#define OFF_CNORM   2080   // 32
#define OFF_PART    2112   // 256
#define HDR_BYTES   9472
// byte offsets after header (meta only, ~13 MB):
#define OFF_REC     HDR_BYTES                     // u32[NG]    1 MB
#define OFF_CPK     (OFF_REC + 4L * NG)           // uint4-grouped conf pairs, 4 MB
#define OFF_CEM     (OFF_CPK + 16L * NG)          // float4[NG] 4 MB
#define OFF_CEA     (OFF_CEM + 16L * NG)          // float4[NG] 4 MB

#define ELEM(v,e) ((e)==0?(v).x:(e)==1?(v).y:(e)==2?(v).z:(v).w)
#define W32(q,i)  ((i)==0?(q).x:(i)==1?(q).y:(i)==2?(q).z:(q).w)

__device__ __forceinline__ float wave_sum64(float v) {
#pragma unroll
  for (int off = 32; off > 0; off >>= 1) v += __shfl_xor(v, off, 64);
  return v;
}
__device__ __forceinline__ unsigned short f2bf(float f) {  // RNE
  unsigned u = __float_as_uint(f);
  return (unsigned short)((u + 0x7fffu + ((u >> 16) & 1u)) >> 16);
}

// -------- Pass A2s: per-pixel stats only (~15 us) --------
__global__ __launch_bounds__(256) void passA2s(
    const float* __restrict__ pm, const float* __restrict__ pa,
    unsigned* __restrict__ recu, uint4* __restrict__ cpk4,
    float4* __restrict__ cem4, float4* __restrict__ cea4) {
  int p4 = blockIdx.x * 256 + threadIdx.x;
  int b = p4 >> 16;
  int px4 = p4 & 0xFFFF;
  const float4* xb = (const float4*)pm + (((long)b * NC) << 16) + px4;
  const float4* yb = (const float4*)pa + (((long)b * NC) << 16) + px4;
  float4 X0 = xb[0], X1 = xb[1 << 16], X2 = xb[2 << 16], X3 = xb[3 << 16];
  float4 Y0 = yb[0], Y1 = yb[1 << 16], Y2 = yb[2 << 16], Y3 = yb[3 << 16];
  float4 cem, cea;
  uint4 cpk;
  unsigned ru = 0;
#pragma unroll
  for (int e = 0; e < 4; ++e) {
    float x0 = ELEM(X0, e), x1 = ELEM(X1, e), x2 = ELEM(X2, e), x3 = ELEM(X3, e);
    float y0 = ELEM(Y0, e), y1 = ELEM(Y1, e), y2 = ELEM(Y2, e), y3 = ELEM(Y3, e);
    int hm = 0; float bm = x0;
    if (x1 > bm) { bm = x1; hm = 1; }
    if (x2 > bm) { bm = x2; hm = 2; }
    if (x3 > bm) { bm = x3; hm = 3; }
    int ha = 0; float ba = y0;
    if (y1 > ba) { ba = y1; ha = 1; }
    if (y2 > ba) { ba = y2; ha = 2; }
    if (y3 > ba) { ba = y3; ha = 3; }
    float sem = expf(x0 - bm) + expf(x1 - bm) + expf(x2 - bm) + expf(x3 - bm);
    float sea = expf(y0 - ba) + expf(y1 - ba) + expf(y2 - ba) + expf(y3 - ba);
    float confm = 1.0f / sem, confa = 1.0f / sea;
    int mk = (confm >= confa) ? 1 : 0;
    int lab = mk ? hm : ha;
    float xl = lab == 0 ? x0 : lab == 1 ? x1 : lab == 2 ? x2 : x3;
    float yl = lab == 0 ? y0 : lab == 1 ? y1 : lab == 2 ? y2 : y3;
    float vem = bm - xl + logf(sem);
    float vea = ba - yl + logf(sea);
    unsigned pk = (unsigned)f2bf(confm) | ((unsigned)f2bf(confa) << 16);
    if (e == 0) { cem.x = vem; cea.x = vea; cpk.x = pk; }
    if (e == 1) { cem.y = vem; cea.y = vea; cpk.y = pk; }
    if (e == 2) { cem.z = vem; cea.z = vea; cpk.z = pk; }
    if (e == 3) { cem.w = vem; cea.w = vea; cpk.w = pk; }
    ru |= (unsigned)(hm | (ha << 2) | (mk << 4)) << (8 * e);
  }
  cem4[p4] = cem; cea4[p4] = cea; cpk4[p4] = cpk; recu[p4] = ru;
}

// -------- countK: per-(b,map,cls) pixel counts from recu (~3 us) ---------
__global__ __launch_bounds__(256) void countK(const unsigned* __restrict__ recu,
                                              float* __restrict__ counts) {
  int b = blockIdx.y;
  int t = blockIdx.x * 256 + threadIdx.x;
  float c[8];
#pragma unroll
  for (int j = 0; j < 8; ++j) c[j] = 0.f;
#pragma unroll
  for (int k = 0; k < 8; ++k) {
    unsigned ru = recu[(b << 16) + t + k * 8192];
#pragma unroll
    for (int e = 0; e < 4; ++e) {
      unsigned r = (ru >> (8 * e)) & 0xffu;
      int hm = r & 3, ha = (r >> 2) & 3;
      c[0] += hm == 0 ? 1.f : 0.f; c[1] += hm == 1 ? 1.f : 0.f;
      c[2] += hm == 2 ? 1.f : 0.f; c[3] += hm == 3 ? 1.f : 0.f;
      c[4] += ha == 0 ? 1.f : 0.f; c[5] += ha == 1 ? 1.f : 0.f;
      c[6] += ha == 2 ? 1.f : 0.f; c[7] += ha == 3 ? 1.f : 0.f;
    }
  }
  int lane = threadIdx.x & 63;
#pragma unroll
  for (int j = 0; j < 8; ++j) {
    float v = wave_sum64(c[j]);
    if (lane == 0) atomicAdd(&counts[(j >> 2) * 16 + b * 4 + (j & 3)], v);
  }
}

// -------- passB5: center sums (R19 best config: 94 us, 12-variant floor) --
// 2 d-planes/block; acc[8][2] register accumulate; unroll 4; (256,2).
// This is the measured optimum of the window-depth x occupancy trade:
// deeper windows (R21: VGPR 168) drop occupancy to 10% and LOSE; shallower
// (R14: unroll 2) or in-loop cross-lane ops also lose. hipcc's scheduler
// caps carried-accumulator cold streams at ~3 TB/s here.
__global__ __launch_bounds__(256, 2) void passB5(
    const float* __restrict__ fm, const float* __restrict__ fa,
    const unsigned* __restrict__ recu, const uint4* __restrict__ cpk4,
    float* __restrict__ sums) {
  __shared__ float lred[4][16];     // [wave][dj*8 + bin]
  int b = blockIdx.y >> 4;
  int dp = blockIdx.y & 15;
  int d0 = dp * 2;
  int wave = threadIdx.x >> 6, lane = threadIdx.x & 63;
  bool b0 = lane & 1, b1 = lane & 2, b2 = lane & 4;

  const float4* fm0 = (const float4*)fm + (((long)(b * ND + d0)) << 16);
  const float4* fa0 = (const float4*)fa + (((long)(b * ND + d0)) << 16);
  const float4* fm1 = fm0 + (1L << 16);
  const float4* fa1 = fa0 + (1L << 16);
  const unsigned* ruP = recu + ((long)b << 16);
  const uint4* ckP = cpk4 + ((long)b << 16);

  float acc[8][2];                  // [bin][dj] — constant-indexed only
#pragma unroll
  for (int c = 0; c < 8; ++c) {
    acc[c][0] = 0.f;
    acc[c][1] = 0.f;
  }

#pragma unroll 4
  for (int k = 0; k < 8; ++k) {
    int g = blockIdx.x * 2048 + k * 256 + threadIdx.x;
    unsigned ru = ruP[g];
    uint4 ck = ckP[g];
    float4 vm0 = fm0[g];
    float4 va0 = fa0[g];
    float4 vm1 = fm1[g];
    float4 va1 = fa1[g];
#pragma unroll
    for (int e = 0; e < 4; ++e) {
      unsigned r = (ru >> (8 * e)) & 0xffu;
      unsigned pk = W32(ck, e);
      int hm = r & 3, ha = (r >> 2) & 3, mk = (r >> 4) & 1;
      float cm = __uint_as_float(pk << 16);
      float ca = __uint_as_float(pk & 0xffff0000u);
      float p0 = mk ? ELEM(vm0, e) : ELEM(va0, e);
      float p1 = mk ? ELEM(vm1, e) : ELEM(va1, e);
#pragma unroll
      for (int c = 0; c < 4; ++c) {
        float wm = (hm == c) ? cm : 0.f;
        float wa = (ha == c) ? ca : 0.f;
        acc[c][0] = fmaf(wm, p0, acc[c][0]);
        acc[c][1] = fmaf(wm, p1, acc[c][1]);
        acc[4 + c][0] = fmaf(wa, p0, acc[4 + c][0]);
        acc[4 + c][1] = fmaf(wa, p1, acc[4 + c][1]);
      }
    }
  }

  // epilogue: per dj, multi-value butterfly (10 shfl), shuffles ONLY here
#pragma unroll
  for (int j = 0; j < 2; ++j) {
    float v0 = acc[0][j], v1 = acc[1][j], v2 = acc[2][j], v3 = acc[3][j];
    float v4 = acc[4][j], v5 = acc[5][j], v6 = acc[6][j], v7 = acc[7][j];
    float w0 = (b0 ? v1 : v0) + __shfl_xor(b0 ? v0 : v1, 1, 64);
    float w1 = (b0 ? v3 : v2) + __shfl_xor(b0 ? v2 : v3, 1, 64);
    float w2 = (b0 ? v5 : v4) + __shfl_xor(b0 ? v4 : v5, 1, 64);
    float w3 = (b0 ? v7 : v6) + __shfl_xor(b0 ? v6 : v7, 1, 64);
    float x0 = (b1 ? w1 : w0) + __shfl_xor(b1 ? w0 : w1, 2, 64);
    float x1 = (b1 ? w3 : w2) + __shfl_xor(b1 ? w2 : w3, 2, 64);
    float y = (b2 ? x1 : x0) + __shfl_xor(b2 ? x0 : x1, 4, 64);
    y += __shfl_xor(y, 8, 64);
    y += __shfl_xor(y, 16, 64);
    y += __shfl_xor(y, 32, 64);
    if (lane < 8) lred[wave][j * 8 + lane] = y;
  }
  __syncthreads();
  if (threadIdx.x < 16) {
    int t = threadIdx.x;            // t = dj*8 + bin
    float v = lred[0][t] + lred[1][t] + lred[2][t] + lred[3][t];
    int dj = t >> 3, bin = t & 7;
    int map = bin >> 2, cls = bin & 3;
    atomicAdd(&sums[((map * NB + b) * NC + cls) * ND + d0 + dj], v);
  }
}

// -------- Pass C: finalize centers + norms (1 block) --------
__global__ __launch_bounds__(1024) void passC(
    const float* __restrict__ sums, const float* __restrict__ counts,
    float* __restrict__ centers, float* __restrict__ cnorm) {
  int t = threadIdx.x;
  int g = t >> 5;
  float cv = sums[t] / fmaxf(counts[g], 1.f);
  centers[t] = cv;
  float s = cv * cv;
#pragma unroll
  for (int off = 16; off > 0; off >>= 1) s += __shfl_xor(s, off, 32);
  if ((t & 31) == 0) cnorm[g] = fmaxf(sqrtf(s), EPSF);
}

// -------- Pass D: cosine + weighted reductions (~45 us, L3-warm 6 TB/s) ---
__global__ __launch_bounds__(256) void passDf32(
    const float* __restrict__ fm, const float* __restrict__ fa,
    const unsigned* __restrict__ recu, const float4* __restrict__ cem4,
    const float4* __restrict__ cea4, const float* __restrict__ centers,
    const float* __restrict__ cnorm, float* __restrict__ part) {
  __shared__ float sc[1024];
  __shared__ float scn[32];
  __shared__ float red[4][4];
  for (int i = threadIdx.x; i < 1024; i += 256) {
    int d = i & 31, cls = (i >> 5) & 3, bb = (i >> 7) & 3, mp = i >> 9;
    sc[d * 32 + mp * 16 + bb * 4 + cls] = centers[i];
  }
  if (threadIdx.x < 32) scn[threadIdx.x] = cnorm[threadIdx.x];
  __syncthreads();

  int p4 = blockIdx.x * 256 + threadIdx.x;
  int b = p4 >> 16;
  int px4 = p4 & 0xFFFF;
  unsigned ru = recu[p4];
  int im[4], ia[4], mk[4];
#pragma unroll
  for (int e = 0; e < 4; ++e) {
    unsigned r = (ru >> (8 * e)) & 0xffu;
    im[e] = b * 4 + (r & 3);
    ia[e] = 16 + b * 4 + ((r >> 2) & 3);
    mk[e] = (r >> 4) & 1;
  }
  const float4* fmb = (const float4*)fm + (((long)(b * ND)) << 16) + px4;
  const float4* fab = (const float4*)fa + (((long)(b * ND)) << 16) + px4;
  float4 nm = {0.f, 0.f, 0.f, 0.f}, na = {0.f, 0.f, 0.f, 0.f},
         fn2 = {0.f, 0.f, 0.f, 0.f};
#pragma unroll 16
  for (int d = 0; d < ND; ++d) {
    float4 vm = fmb[(long)d << 16];
    float4 va = fab[(long)d << 16];
#pragma unroll
    for (int e = 0; e < 4; ++e) {
      float ps = mk[e] ? ELEM(vm, e) : ELEM(va, e);
      float cim = sc[d * 32 + im[e]];
      float cia = sc[d * 32 + ia[e]];
      if (e == 0) { nm.x = fmaf(ps, cim, nm.x); na.x = fmaf(ps, cia, na.x); fn2.x = fmaf(ps, ps, fn2.x); }
      if (e == 1) { nm.y = fmaf(ps, cim, nm.y); na.y = fmaf(ps, cia, na.y); fn2.y = fmaf(ps, ps, fn2.y); }
      if (e == 2) { nm.z = fmaf(ps, cim, nm.z); na.z = fmaf(ps, cia, na.z); fn2.z = fmaf(ps, ps, fn2.z); }
      if (e == 3) { nm.w = fmaf(ps, cim, nm.w); na.w = fmaf(ps, cia, na.w); fn2.w = fmaf(ps, ps, fn2.w); }
    }
  }
  float4 cem = cem4[p4], cea = cea4[p4];
  float s0 = 0.f, s1 = 0.f, s2 = 0.f, s3 = 0.f;
#pragma unroll
  for (int e = 0; e < 4; ++e) {
    float fn = fmaxf(sqrtf(ELEM(fn2, e)), EPSF);
    float rm = ELEM(nm, e) / (fn * scn[im[e]]);
    float ra = ELEM(na, e) / (fn * scn[ia[e]]);
    s0 = fmaf(ELEM(cem, e), ra, s0);
    s1 += ra;
    s2 = fmaf(ELEM(cea, e), rm, s2);
    s3 += rm;
  }
  s0 = wave_sum64(s0); s1 = wave_sum64(s1);
  s2 = wave_sum64(s2); s3 = wave_sum64(s3);
  int wave = threadIdx.x >> 6, lane = threadIdx.x & 63;
  if (lane == 0) { red[wave][0] = s0; red[wave][1] = s1; red[wave][2] = s2; red[wave][3] = s3; }
  __syncthreads();
  if (threadIdx.x < 4) {
    float v = red[0][threadIdx.x] + red[1][threadIdx.x] +
              red[2][threadIdx.x] + red[3][threadIdx.x];
    atomicAdd(&part[(blockIdx.x & 63) * 4 + threadIdx.x], v);
  }
}

// -------- Pass E: final scalar --------
__global__ __launch_bounds__(64) void passE(const float* __restrict__ part,
                                            float* __restrict__ out) {
  int t = threadIdx.x;
  float a0 = part[t * 4 + 0], a1 = part[t * 4 + 1];
  float a2 = part[t * 4 + 2], a3 = part[t * 4 + 3];
  a0 = wave_sum64(a0); a1 = wave_sum64(a1);
  a2 = wave_sum64(a2); a3 = wave_sum64(a3);
  if (t == 0) out[0] = a0 / a1 + a2 / a3;
}

extern "C" void kernel_launch(void* const* d_in, const int* in_sizes, int n_in,
                              void* d_out, int out_size, void* d_ws, size_t ws_size,
                              hipStream_t stream) {
  const float* pm = (const float*)d_in[0];
  const float* pa = (const float*)d_in[1];
  const float* fm = (const float*)d_in[2];
  const float* fa = (const float*)d_in[3];

  float* wsf = (float*)d_ws;
  float* sums = wsf + OFF_SUMS;
  float* counts = wsf + OFF_COUNTS;
  float* centers = wsf + OFF_CENTERS;
  float* cnorm = wsf + OFF_CNORM;
  float* part = wsf + OFF_PART;
  char* wsb = (char*)d_ws;
  unsigned* recu = (unsigned*)(wsb + OFF_REC);
  uint4* cpk4 = (uint4*)(wsb + OFF_CPK);
  float4* cem4 = (float4*)(wsb + OFF_CEM);
  float4* cea4 = (float4*)(wsb + OFF_CEA);

  hipMemsetAsync(d_ws, 0, HDR_BYTES, stream);
  passA2s<<<1024, 256, 0, stream>>>(pm, pa, recu, cpk4, cem4, cea4);
  countK<<<dim3(32, 4), 256, 0, stream>>>(recu, counts);
  passB5<<<dim3(32, 64), 256, 0, stream>>>(fm, fa, recu, cpk4, sums);
  passC<<<1, 1024, 0, stream>>>(sums, counts, centers, cnorm);
  passDf32<<<1024, 256, 0, stream>>>(fm, fa, recu, cem4, cea4, centers,
                                     cnorm, part);
  passE<<<1, 64, 0, stream>>>(part, (float*)d_out);
}